// Round 10
// baseline (148.418 us; speedup 1.0000x reference)
//
#include <hip/hip_runtime.h>

// SSIM loss (R10): barrier-free wave-independent tiles with CORRECT in-wave
// LDS ordering: __threadfence_block() between commit (ds_write) and hconv
// (ds_read of other lanes' data). No s_barrier in the main loop — waves stay
// independent; the fence only pins compiler/DS instruction order.
// Each wave: 64-col x 16-row output tile, private LDS row buffer, packed
// f32x2 compute (horizontal 11-tap from LDS, vertical 11-tap via 12-slot
// register ring, shift-by-2), SSIM, per-wave reduce, 1 atomic/block.

typedef float f32x2 __attribute__((ext_vector_type(2)));

static __device__ __forceinline__ f32x2 mk2(float x, float y) {
    f32x2 r; r.x = x; r.y = y; return r;
}

constexpr int KW   = 11;
constexpr int HALF = 5;
constexpr int IMG_H = 512;
constexpr int IMG_W = 512;
constexpr int NB   = 32;
constexpr int NCH  = 3;
constexpr int TCW  = 64;                   // output cols per wave
constexpr int TRW  = 16;                   // output rows per wave
constexpr int NP   = (TRW + 2*HALF) / 2;   // 13 row-pairs (26 rows)
constexpr int WPB  = 4;                    // waves per block
constexpr int BT   = WPB * 64;             // 256 threads
constexpr int LSLOT = 80;                  // 74 used (64 main + 10 halo)

__global__ __launch_bounds__(BT)
void ssim_fused(const float* __restrict__ pred,
                const float* __restrict__ targ,
                const float* __restrict__ win,
                float* __restrict__ out)
{
    __shared__ f32x2 lbuf[WPB][2][LSLOT];   // wave-private: [wid][row-of-pair][slot]
    __shared__ float red[WPB];

    const int tid  = threadIdx.x;
    const int lane = tid & 63;
    const int wid  = tid >> 6;
    const int gw   = blockIdx.x * WPB + wid;   // 0..8191
    const int ct   = gw & 7;                   // col-tile
    const int st   = (gw >> 3) & 31;           // row-strip
    const int img  = gw >> 8;                  // image
    const int c0   = ct * TCW;
    const int R0   = st * TRW;

    // exact 1-D gaussian (symmetric, 6 unique) from the passed 2-D window
    float gs[6];
    {
        float g5 = sqrtf(win[HALF*KW + HALF]);
        #pragma unroll
        for (int j = 0; j < 6; ++j) gs[j] = win[HALF*KW + j] / g5;
    }
    auto W = [&](int j) { return gs[j <= 5 ? j : 10 - j]; };  // j static

    const size_t ims = (size_t)IMG_H * IMG_W;
    const float* pb = pred + (size_t)img * NCH * ims;
    const float* tb = targ + (size_t)img * NCH * ims;

    // slot s holds col c0-5+s: main s=lane (cols c0-5..c0+58),
    // halo s=64+l for lanes l<10 (cols c0+59..c0+68)
    const int cm  = c0 - HALF + lane;
    const int chc = c0 + 59 + lane;
    const bool okm = (unsigned)cm  < (unsigned)IMG_W;
    const bool okh = (lane < 10) && ((unsigned)chc < (unsigned)IMG_W);

    float a0,a1,a2,b0,b1,b2;     // main col: P ch0..2, T ch0..2
    float e0,e1,e2,e3,e4,e5;     // halo col
    auto issue = [&](int rowidx) {
        int r = R0 - HALF + rowidx;
        if ((unsigned)r < (unsigned)IMG_H) {
            size_t base = (size_t)r * IMG_W;
            if (okm) { size_t a = base + cm;
                a0=pb[a]; a1=pb[a+ims]; a2=pb[a+2*ims];
                b0=tb[a]; b1=tb[a+ims]; b2=tb[a+2*ims];
            } else { a0=a1=a2=b0=b1=b2=0.f; }
            if (okh) { size_t a = base + chc;
                e0=pb[a]; e1=pb[a+ims]; e2=pb[a+2*ims];
                e3=tb[a]; e4=tb[a+ims]; e5=tb[a+2*ims];
            } else { e0=e1=e2=e3=e4=e5=0.f; }
        } else {
            a0=a1=a2=b0=b1=b2=0.f;
            e0=e1=e2=e3=e4=e5=0.f;
        }
    };
    const float inv3 = 1.f/3.f;
    auto commit = [&](int slot) {
        lbuf[wid][slot][lane] = mk2((a0+a1+a2)*inv3, (b0+b1+b2)*inv3);
        if (lane < 10)
            lbuf[wid][slot][64+lane] = mk2((e0+e1+e2)*inv3, (e3+e4+e5)*inv3);
    };

    // 12-slot vertical ring, plane-packed (statically indexed everywhere)
    f32x2 rMU[12], rSQ[12];   // (hP, hT), (hP2, hT2)
    float rPT[12];            // hPT
    #pragma unroll
    for (int k = 0; k < 12; ++k) {
        rMU[k] = mk2(0.f, 0.f); rSQ[k] = mk2(0.f, 0.f); rPT[k] = 0.f;
    }

    auto hconv = [&](int slot, f32x2& oMU, f32x2& oSQ, float& oPT) {
        const f32x2* Lr = &lbuf[wid][slot][lane];
        f32x2 mu = mk2(0.f, 0.f), sq = mk2(0.f, 0.f);
        float pt = 0.f;
        #pragma unroll
        for (int j = 0; j < KW; ++j) {
            const float w = W(j);
            f32x2 v = Lr[j];                   // ds_read_b64, 2-way free
            mu += v * w; sq += (v * v) * w; pt += (v.x * v.y) * w;
        }
        oMU = mu; oSQ = sq; oPT = pt;
    };

    const float C1 = 1e-4f, C2 = 9e-4f;
    float acc = 0.f;

    issue(0);
    for (int i = 0; i < NP; ++i) {
        commit(0);                  // write slot 0 (rowidx 2i)
        __threadfence_block();      // order ds_write -> other-lane ds_read
        issue(2*i + 1);             // prefetch rowidx 2i+1 (after fence!)
        hconv(0, rMU[10], rSQ[10], rPT[10]);   // consume row 2i
        commit(1);                  // write slot 1 (rowidx 2i+1)
        __threadfence_block();
        if (i + 1 < NP) issue(2*i + 2);        // prefetch next pair's row
        hconv(1, rMU[11], rSQ[11], rPT[11]);   // consume row 2i+1

        if (i >= 5) {               // outputs rows R0+2i-10, R0+2i-9
            #pragma unroll
            for (int off = 0; off < 2; ++off) {
                f32x2 m = mk2(0.f, 0.f), e = mk2(0.f, 0.f);
                float ept = 0.f;
                #pragma unroll
                for (int k = 0; k < KW; ++k) {
                    const float w = W(k);
                    m += rMU[off + k] * w;
                    e += rSQ[off + k] * w;
                    ept += rPT[off + k] * w;
                }
                f32x2 msq = m * m;                 // (m11, m22)
                float m12 = m.x * m.y;
                f32x2 s = e - msq;                 // (s1, s2)
                float s12 = ept - m12;
                float num = (2.f * m12 + C1) * (2.f * s12 + C2);
                float den = (msq.x + msq.y + C1) * (s.x + s.y + C2);
                acc += 1.f - num * __builtin_amdgcn_rcpf(den);
            }
        }

        #pragma unroll
        for (int k = 0; k < 10; ++k) {
            rMU[k] = rMU[k + 2]; rSQ[k] = rSQ[k + 2]; rPT[k] = rPT[k + 2];
        }
    }

    // per-wave reduce, then one barrier + one atomic per block
    #pragma unroll
    for (int off = 32; off >= 1; off >>= 1)
        acc += __shfl_down(acc, off, 64);
    if (lane == 0) red[wid] = acc;
    __syncthreads();
    if (tid == 0) {
        float s = 0.f;
        #pragma unroll
        for (int w = 0; w < WPB; ++w) s += red[w];
        atomicAdd(out, s * (1.0f / ((float)NB * IMG_H * IMG_W)));
    }
}

extern "C" void kernel_launch(void* const* d_in, const int* in_sizes, int n_in,
                              void* d_out, int out_size, void* d_ws, size_t ws_size,
                              hipStream_t stream) {
    const float* pred = (const float*)d_in[0];
    const float* targ = (const float*)d_in[1];
    const float* win  = (const float*)d_in[2];
    float* out = (float*)d_out;

    hipMemsetAsync(out, 0, sizeof(float), stream);

    dim3 grid((NB * 32 * 8) / WPB);   // 8192 waves / 4 = 2048 blocks
    ssim_fused<<<grid, BT, 0, stream>>>(pred, targ, win, out);
}

// Round 11
// 147.843 us; speedup vs baseline: 1.0039x; 1.0039x over previous
//
#include <hip/hip_runtime.h>

// SSIM loss (R11): barrier-free wave-independent tiles (R10 structure) with
// the runtime fence replaced by a ZERO-COST compile-time ordering fence:
//   asm volatile("" ::: "memory") + __builtin_amdgcn_sched_barrier(0)
// The DS unit retires a wave's LDS ops in order, so only compiler reordering
// must be prevented — no s_waitcnt, no s_barrier. Waves free-run.
// Each wave: 64-col x 16-row output tile, private LDS row buffer, packed
// f32x2 compute (horizontal 11-tap from LDS, vertical 11-tap via 12-slot
// register ring, shift-by-2), SSIM, per-wave reduce, 1 atomic/block.

typedef float f32x2 __attribute__((ext_vector_type(2)));

static __device__ __forceinline__ f32x2 mk2(float x, float y) {
    f32x2 r; r.x = x; r.y = y; return r;
}

// compile-time LDS ordering fence: no instructions emitted
static __device__ __forceinline__ void lds_order_fence() {
    asm volatile("" ::: "memory");
    __builtin_amdgcn_sched_barrier(0);
}

constexpr int KW   = 11;
constexpr int HALF = 5;
constexpr int IMG_H = 512;
constexpr int IMG_W = 512;
constexpr int NB   = 32;
constexpr int NCH  = 3;
constexpr int TCW  = 64;                   // output cols per wave
constexpr int TRW  = 16;                   // output rows per wave
constexpr int NP   = (TRW + 2*HALF) / 2;   // 13 row-pairs (26 rows)
constexpr int WPB  = 4;                    // waves per block
constexpr int BT   = WPB * 64;             // 256 threads
constexpr int LSLOT = 80;                  // 74 used (64 main + 10 halo)

__global__ __launch_bounds__(BT)
void ssim_fused(const float* __restrict__ pred,
                const float* __restrict__ targ,
                const float* __restrict__ win,
                float* __restrict__ out)
{
    __shared__ f32x2 lbuf[WPB][2][LSLOT];   // wave-private: [wid][row-of-pair][slot]
    __shared__ float red[WPB];

    const int tid  = threadIdx.x;
    const int lane = tid & 63;
    const int wid  = tid >> 6;
    const int gw   = blockIdx.x * WPB + wid;   // 0..8191
    const int ct   = gw & 7;                   // col-tile
    const int st   = (gw >> 3) & 31;           // row-strip
    const int img  = gw >> 8;                  // image
    const int c0   = ct * TCW;
    const int R0   = st * TRW;

    // exact 1-D gaussian (symmetric, 6 unique) from the passed 2-D window
    float gs[6];
    {
        float g5 = sqrtf(win[HALF*KW + HALF]);
        #pragma unroll
        for (int j = 0; j < 6; ++j) gs[j] = win[HALF*KW + j] / g5;
    }
    auto W = [&](int j) { return gs[j <= 5 ? j : 10 - j]; };  // j static

    const size_t ims = (size_t)IMG_H * IMG_W;
    const float* pb = pred + (size_t)img * NCH * ims;
    const float* tb = targ + (size_t)img * NCH * ims;

    // slot s holds col c0-5+s: main s=lane (cols c0-5..c0+58),
    // halo s=64+l for lanes l<10 (cols c0+59..c0+68)
    const int cm  = c0 - HALF + lane;
    const int chc = c0 + 59 + lane;
    const bool okm = (unsigned)cm  < (unsigned)IMG_W;
    const bool okh = (lane < 10) && ((unsigned)chc < (unsigned)IMG_W);

    float a0,a1,a2,b0,b1,b2;     // main col: P ch0..2, T ch0..2
    float e0,e1,e2,e3,e4,e5;     // halo col
    auto issue = [&](int rowidx) {
        int r = R0 - HALF + rowidx;
        if ((unsigned)r < (unsigned)IMG_H) {
            size_t base = (size_t)r * IMG_W;
            if (okm) { size_t a = base + cm;
                a0=pb[a]; a1=pb[a+ims]; a2=pb[a+2*ims];
                b0=tb[a]; b1=tb[a+ims]; b2=tb[a+2*ims];
            } else { a0=a1=a2=b0=b1=b2=0.f; }
            if (okh) { size_t a = base + chc;
                e0=pb[a]; e1=pb[a+ims]; e2=pb[a+2*ims];
                e3=tb[a]; e4=tb[a+ims]; e5=tb[a+2*ims];
            } else { e0=e1=e2=e3=e4=e5=0.f; }
        } else {
            a0=a1=a2=b0=b1=b2=0.f;
            e0=e1=e2=e3=e4=e5=0.f;
        }
    };
    const float inv3 = 1.f/3.f;
    auto commit = [&](int slot) {
        lbuf[wid][slot][lane] = mk2((a0+a1+a2)*inv3, (b0+b1+b2)*inv3);
        if (lane < 10)
            lbuf[wid][slot][64+lane] = mk2((e0+e1+e2)*inv3, (e3+e4+e5)*inv3);
    };

    // 12-slot vertical ring, plane-packed (statically indexed everywhere)
    f32x2 rMU[12], rSQ[12];   // (hP, hT), (hP2, hT2)
    float rPT[12];            // hPT
    #pragma unroll
    for (int k = 0; k < 12; ++k) {
        rMU[k] = mk2(0.f, 0.f); rSQ[k] = mk2(0.f, 0.f); rPT[k] = 0.f;
    }

    auto hconv = [&](int slot, f32x2& oMU, f32x2& oSQ, float& oPT) {
        const f32x2* Lr = &lbuf[wid][slot][lane];
        f32x2 mu = mk2(0.f, 0.f), sq = mk2(0.f, 0.f);
        float pt = 0.f;
        #pragma unroll
        for (int j = 0; j < KW; ++j) {
            const float w = W(j);
            f32x2 v = Lr[j];                   // ds_read_b64, 2-way free
            mu += v * w; sq += (v * v) * w; pt += (v.x * v.y) * w;
        }
        oMU = mu; oSQ = sq; oPT = pt;
    };

    const float C1 = 1e-4f, C2 = 9e-4f;
    float acc = 0.f;

    issue(0);
    for (int i = 0; i < NP; ++i) {
        commit(0);                  // write slot 0 (rowidx 2i)
        lds_order_fence();          // pin ds_write -> other-lane ds_read order
        issue(2*i + 1);             // prefetch rowidx 2i+1 (stays in flight)
        hconv(0, rMU[10], rSQ[10], rPT[10]);   // consume row 2i
        commit(1);                  // write slot 1 (rowidx 2i+1)
        lds_order_fence();
        if (i + 1 < NP) issue(2*i + 2);        // prefetch next pair's row
        hconv(1, rMU[11], rSQ[11], rPT[11]);   // consume row 2i+1

        if (i >= 5) {               // outputs rows R0+2i-10, R0+2i-9
            #pragma unroll
            for (int off = 0; off < 2; ++off) {
                f32x2 m = mk2(0.f, 0.f), e = mk2(0.f, 0.f);
                float ept = 0.f;
                #pragma unroll
                for (int k = 0; k < KW; ++k) {
                    const float w = W(k);
                    m += rMU[off + k] * w;
                    e += rSQ[off + k] * w;
                    ept += rPT[off + k] * w;
                }
                f32x2 msq = m * m;                 // (m11, m22)
                float m12 = m.x * m.y;
                f32x2 s = e - msq;                 // (s1, s2)
                float s12 = ept - m12;
                float num = (2.f * m12 + C1) * (2.f * s12 + C2);
                float den = (msq.x + msq.y + C1) * (s.x + s.y + C2);
                acc += 1.f - num * __builtin_amdgcn_rcpf(den);
            }
        }

        #pragma unroll
        for (int k = 0; k < 10; ++k) {
            rMU[k] = rMU[k + 2]; rSQ[k] = rSQ[k + 2]; rPT[k] = rPT[k + 2];
        }
    }

    // per-wave reduce, then one barrier + one atomic per block
    #pragma unroll
    for (int off = 32; off >= 1; off >>= 1)
        acc += __shfl_down(acc, off, 64);
    if (lane == 0) red[wid] = acc;
    __syncthreads();
    if (tid == 0) {
        float s = 0.f;
        #pragma unroll
        for (int w = 0; w < WPB; ++w) s += red[w];
        atomicAdd(out, s * (1.0f / ((float)NB * IMG_H * IMG_W)));
    }
}

extern "C" void kernel_launch(void* const* d_in, const int* in_sizes, int n_in,
                              void* d_out, int out_size, void* d_ws, size_t ws_size,
                              hipStream_t stream) {
    const float* pred = (const float*)d_in[0];
    const float* targ = (const float*)d_in[1];
    const float* win  = (const float*)d_in[2];
    float* out = (float*)d_out;

    hipMemsetAsync(out, 0, sizeof(float), stream);

    dim3 grid((NB * 32 * 8) / WPB);   // 8192 waves / 4 = 2048 blocks
    ssim_fused<<<grid, BT, 0, stream>>>(pred, targ, win, out);
}

// Round 12
// 132.070 us; speedup vs baseline: 1.1238x; 1.1194x over previous
//
#include <hip/hip_runtime.h>

// SSIM loss (R12): barrier-free wave tiles + U/V basis + unrolled mod-11 ring.
//  - U=P+T, V=P-T: SSIM needs only conv(U),conv(V),conv(U^2),conv(V^2)
//    (4 planes, not 5): 2mu1mu2=(muU^2-muV^2)/2, mu1^2+mu2^2=(muU^2+muV^2)/2,
//    2sig12=(EUU-EVV)/2-2mu1mu2, sig1+sig2=(EUU+EVV)/2-(mu1^2+mu2^2).
//  - 11-slot register ring, 26-row full unroll -> static indices, no shifts.
//  - wave stages 64 cols, outputs 54; no halo loads; weights in SGPRs.
//  - goal: VGPR <= 64 => 8 waves/SIMD; 10240 waves total, no s_barrier.

typedef float f32x2 __attribute__((ext_vector_type(2)));

static __device__ __forceinline__ f32x2 mk2(float x, float y) {
    f32x2 r; r.x = x; r.y = y; return r;
}
// compile-time LDS ordering fence (no instructions) — proven in R10->R11
static __device__ __forceinline__ void lds_order_fence() {
    asm volatile("" ::: "memory");
    __builtin_amdgcn_sched_barrier(0);
}
static __device__ __forceinline__ float uniformf(float v) {
    return __uint_as_float(__builtin_amdgcn_readfirstlane(__float_as_uint(v)));
}

constexpr int KW = 11, HALF = 5;
constexpr int IMG_H = 512, IMG_W = 512, NB = 32, NCH = 3;
constexpr int OC  = 54;                  // output cols per wave
constexpr int NCT = 10;                  // col tiles: 10*54 = 540 >= 512
constexpr int TRW = 16;                  // output rows per wave
constexpr int NRS = IMG_H / TRW;         // 32 row strips
constexpr int NROWS = TRW + 2 * HALF;    // 26 staged rows
constexpr int WPB = 4;
constexpr int BT  = WPB * 64;
constexpr int LPAD = 80;                 // 64 slots + pad (lanes 54-63 read garbage, masked)

__global__ __launch_bounds__(BT)
void ssim_fused(const float* __restrict__ pred,
                const float* __restrict__ targ,
                const float* __restrict__ win,
                float* __restrict__ out)
{
    __shared__ f32x2 lbuf[WPB][2][LPAD];   // wave-private double-buffered (U,V) row
    __shared__ float red[WPB];

    const int tid  = threadIdx.x;
    const int lane = tid & 63;
    const int wid  = tid >> 6;
    const int gw   = blockIdx.x * WPB + wid;       // 0..10239
    const int ct   = gw % NCT;                     // uniform (SALU magic-div)
    const int rest = gw / NCT;
    const int st   = rest & (NRS - 1);
    const int img  = rest >> 5;
    const int c0   = ct * OC;
    const int R0   = st * TRW;

    // 1-D gaussian (6 unique, symmetric), forced into SGPRs
    float gs[6];
    {
        float g5 = sqrtf(win[HALF * KW + HALF]);
        #pragma unroll
        for (int j = 0; j < 6; ++j) gs[j] = uniformf(win[HALF * KW + j] / g5);
    }
    auto W = [&](int k) { return gs[k <= 5 ? k : 10 - k]; };   // k static

    const size_t ims = (size_t)IMG_H * IMG_W;
    const float* pb = pred + (size_t)img * NCH * ims;
    const float* tb = targ + (size_t)img * NCH * ims;
    const int  cs  = c0 - HALF + lane;                          // staged col
    const bool okc = (unsigned)cs < (unsigned)IMG_W;
    const bool oko = (lane < OC) && ((c0 + lane) < IMG_W);      // output mask

    float a0, a1, a2, b0, b1, b2;                               // landing regs
    auto issue = [&](int j) {
        int r = R0 - HALF + j;                                  // uniform row
        if (((unsigned)r < (unsigned)IMG_H) && okc) {
            size_t a = (size_t)r * IMG_W + cs;
            a0 = pb[a]; a1 = pb[a + ims]; a2 = pb[a + 2 * ims];
            b0 = tb[a]; b1 = tb[a + ims]; b2 = tb[a + 2 * ims];
        } else { a0 = a1 = a2 = b0 = b1 = b2 = 0.f; }
    };
    const float inv3 = 1.f / 3.f;
    auto commit = [&](int j) {
        float sp = a0 + a1 + a2, st_ = b0 + b1 + b2;
        lbuf[wid][j & 1][lane] = mk2((sp + st_) * inv3, (sp - st_) * inv3);
    };

    // 11-slot ring, statically rotated via (const j) % 11 after full unroll
    f32x2 rUV[11], rUV2[11];

    auto hconv = [&](int j) {
        const f32x2* Lr = &lbuf[wid][j & 1][lane];
        f32x2 m = mk2(0.f, 0.f), q = mk2(0.f, 0.f);
        #pragma unroll
        for (int k = 0; k < KW; ++k) {
            const float w = W(k);
            f32x2 v = Lr[k];                // ds_read_b64 offset:k*8, 2-way free
            m += v * w;                     // pk_fma
            q += (v * v) * w;               // pk_mul + pk_fma
        }
        rUV[j % 11] = m; rUV2[j % 11] = q;
    };

    const float C1 = 1e-4f, C2 = 9e-4f;
    float acc = 0.f;

    issue(0);
    #pragma unroll
    for (int j = 0; j < NROWS; ++j) {
        commit(j);                          // waits this row's loads
        lds_order_fence();                  // pin ds_write -> other-lane ds_read
        if (j + 1 < NROWS) issue(j + 1);    // next row in flight under hconv
        hconv(j);

        if (j >= 10) {                      // output row R0 + (j-10)
            const int o = j - 10;
            f32x2 m = mk2(0.f, 0.f), e = mk2(0.f, 0.f);
            #pragma unroll
            for (int k = 0; k < KW; ++k) {
                const float w = W(k);
                m += rUV[(o + k) % 11] * w;     // (muU, muV)
                e += rUV2[(o + k) % 11] * w;    // (EUU, EVV)
            }
            f32x2 msq = m * m;                  // (muU^2, muV^2)
            float d1 = (msq.x - msq.y) * 0.5f;  // 2*mu1*mu2
            float d2 = (msq.x + msq.y) * 0.5f;  // mu1^2 + mu2^2
            float f1 = (e.x - e.y) * 0.5f;      // 2*conv(PT)
            float f2 = (e.x + e.y) * 0.5f;      // conv(P^2)+conv(T^2)
            float num = (d1 + C1) * (f1 - d1 + C2);
            float den = (d2 + C1) * (f2 - d2 + C2);
            if (oko) acc += 1.f - num * __builtin_amdgcn_rcpf(den);
        }
    }

    // per-wave reduce, one barrier + one atomic per block
    #pragma unroll
    for (int off = 32; off >= 1; off >>= 1)
        acc += __shfl_down(acc, off, 64);
    if (lane == 0) red[wid] = acc;
    __syncthreads();
    if (tid == 0) {
        float s = 0.f;
        #pragma unroll
        for (int w = 0; w < WPB; ++w) s += red[w];
        atomicAdd(out, s * (1.0f / ((float)NB * IMG_H * IMG_W)));
    }
}

extern "C" void kernel_launch(void* const* d_in, const int* in_sizes, int n_in,
                              void* d_out, int out_size, void* d_ws, size_t ws_size,
                              hipStream_t stream) {
    const float* pred = (const float*)d_in[0];
    const float* targ = (const float*)d_in[1];
    const float* win  = (const float*)d_in[2];
    float* out = (float*)d_out;

    hipMemsetAsync(out, 0, sizeof(float), stream);

    dim3 grid((NB * NRS * NCT) / WPB);   // 10240 waves / 4 = 2560 blocks
    ssim_fused<<<grid, BT, 0, stream>>>(pred, targ, win, out);
}